// Round 5
// baseline (1188.301 us; speedup 1.0000x reference)
//
#include <hip/hip_runtime.h>

typedef __bf16 bf16x8_t __attribute__((ext_vector_type(8)));
typedef float f32x4_t __attribute__((ext_vector_type(4)));
typedef float f32x2_t __attribute__((ext_vector_type(2)));

#define NSTEPS 100
#define PB0 0u          // partial double-buffer: [0,64K) and [64K,128K)
#define PB1 65536u
#define COMBF 98304u    // comb-input bf16 fragments (post-loop, inside PB1 region)

static __device__ __forceinline__ unsigned short f2bfu(float v) {
  union { __bf16 h; unsigned short u; } c; c.h = (__bf16)v; return c.u;  // RTNE
}
static __device__ __forceinline__ unsigned int pack2bf(float a, float b) {
  return (unsigned)f2bfu(a) | ((unsigned)f2bfu(b) << 16);
}
union BF8U { unsigned int u[4]; bf16x8_t v; };

// VOP3P packed fp32, in-place. Per-half bitwise-identical to v_mul/v_add_f32.
static __device__ __forceinline__ void pk_mul_ip(f32x2_t &a, f32x2_t b) {
  asm("v_pk_mul_f32 %0, %0, %1" : "+v"(a) : "v"(b));
}
static __device__ __forceinline__ void pk_add_ip(f32x2_t &a, f32x2_t b) {
  asm("v_pk_add_f32 %0, %0, %1" : "+v"(a) : "v"(b));
}

static __device__ __forceinline__ bf16x8_t bfrag_f32(const float* __restrict__ p, float s) {
  BF8U r;
#pragma unroll
  for (int i = 0; i < 4; ++i) r.u[i] = pack2bf(p[2*i]*s, p[2*i+1]*s);
  return r.v;
}

static __device__ __forceinline__ void comb_store(unsigned char* ldsp, int k, int row, float v) {
  *(unsigned short*)(ldsp + COMBF +
      (unsigned)((k >> 5)*1024 + (((k >> 3) & 3)*16 + row)*16 + (k & 7)*2)) = f2bfu(v);
}

// 1024 threads = 16 waves = 4 waves/SIMD (128-reg budget). Wave w owns K-slice
// [64w, 64w+64): bfr 32 + c2 16 + mem2 16 + afr 8 regs -> ~110 peak, no spill.
// 2x TLP vs the 512-thread version is the point: the old kernel was ~70% stall.
__global__ __launch_bounds__(1024, 4)
void hybrid_v8(const float* __restrict__ x,
               const float* __restrict__ snn_w1, const float* __restrict__ snn_b1,
               const float* __restrict__ snn_w2, const float* __restrict__ snn_b2,
               const float* __restrict__ nn_w1,  const float* __restrict__ nn_b1,
               const float* __restrict__ nn_w2,  const float* __restrict__ nn_b2,
               const float* __restrict__ conv_w, const float* __restrict__ conv_b,
               const float* __restrict__ fc_w,   const float* __restrict__ fc_b,
               const float* __restrict__ comb_w, const float* __restrict__ comb_b,
               const unsigned short* __restrict__ fcwb, int use_bf,
               float* __restrict__ out)
{
  __shared__ __align__(16) unsigned char lds[131072];
  const int tid  = threadIdx.x;
  const int w    = tid >> 6;        // wave 0..15: K-slice [64w, 64w+64)
  const int l    = tid & 63;
  const int q    = l >> 4;
  const int m    = l & 15;
  const int row0 = blockIdx.x * 16;

  const float* xr = x + (row0 + m)*105;
  const float f0 = xr[0], f1 = xr[1], f2 = xr[2], f3 = xr[3], f4 = xr[4];

  // layer-2 cell owned by this lane: (row = w, col = l)
  const float b2l = snn_b2[l];

  // resident snn_w2 B-fragments: 2 k-chunks x 4 n-tiles (32 regs)
  bf16x8_t bfr[2][4];
#pragma unroll
  for (int ci = 0; ci < 2; ++ci)
#pragma unroll
    for (int nt = 0; nt < 4; ++nt)
      bfr[ci][nt] = bfrag_f32(snn_w2 + (nt*16 + m)*1024 + (w*64 + ci*32) + q*8, 1.f);

  // layer-1 LIF state: 16 cells/lane as 8 f32 pairs (neurons w*64+q*8+ci*32+j, row m)
  f32x2_t c2[8], mem2[8];
  f32x2_t beta2; beta2.x = 0.95f; beta2.y = 0.95f;
  {
    const int kb = w*64 + q*8;
#pragma unroll 1
    for (int ci = 0; ci < 2; ++ci) {
      const float* wp = snn_w1 + (kb + ci*32)*5;
      float wa[40];
#pragma unroll
      for (int u2 = 0; u2 < 10; ++u2) {
        const float4 t4 = *(const float4*)(wp + u2*4);
        wa[u2*4+0] = t4.x; wa[u2*4+1] = t4.y; wa[u2*4+2] = t4.z; wa[u2*4+3] = t4.w;
      }
      float cc[8];
#pragma unroll
      for (int j = 0; j < 8; ++j)
        cc[j] = f0*wa[j*5] + f1*wa[j*5+1] + f2*wa[j*5+2] + f3*wa[j*5+3] + f4*wa[j*5+4]
              + snn_b1[kb + ci*32 + j];
#pragma unroll
      for (int jj = 0; jj < 4; ++jj) {
        f32x2_t t; t.x = cc[2*jj]; t.y = cc[2*jj+1];
        c2[ci*4+jj] = t;
        f32x2_t z; z.x = 0.f; z.y = 0.f;
        mem2[ci*4+jj] = z;
      }
    }
  }

  // spike A-fragments (2 chunks, 8 regs); reset derived from afr words (bit-exact):
  //   lo half: (pw<<16)|0x80000000 -> -1.0f/-0.0f ; hi half: (pw&0x3F800000)|0x80000000
  BF8U afr[2];
#pragma unroll
  for (int ci = 0; ci < 2; ++ci)
#pragma unroll
    for (int j = 0; j < 4; ++j) afr[ci].u[j] = 0u;

  auto lif_step = [&]() {
#pragma unroll
    for (int i = 0; i < 8; ++i) {
      const unsigned pw = afr[i>>2].u[i&3];
      f32x2_t sn;
      sn.x = __uint_as_float((pw << 16) | 0x80000000u);
      sn.y = __uint_as_float((pw & 0x3F800000u) | 0x80000000u);
      pk_mul_ip(mem2[i], beta2);      // mem = ((0.95*mem) + c) + (-sp)  [exact order]
      pk_add_ip(mem2[i], c2[i]);
      pk_add_ip(mem2[i], sn);
      const unsigned lo  = mem2[i].x > 1.f ? 0x3F80u     : 0u;
      const unsigned hi2 = mem2[i].y > 1.f ? 0x3F800000u : 0u;
      afr[i>>2].u[i&3] = lo | hi2;
    }
  };
  lif_step();                        // spikes(t=0)

  // layer-2 LIF (scalar: one cell per lane)
  float m2 = 0.f, s2 = 0.f, cnt = 0.f;

  // partial layout per buffer: [slice:16][row%8][col:64][row/8] f32  (64 KiB)
  const unsigned wbase = (unsigned)(w*4096 + (q&1)*2048 + (q>>1)*4 + m*8);
  const unsigned rbase = (unsigned)((w&7)*512 + (w>>3)*4 + l*8);
  const f32x4_t z4 = {0.f, 0.f, 0.f, 0.f};

  auto l2_update = [&](float cur) {
    m2 = __fsub_rn(__fadd_rn(__fmul_rn(0.95f, m2), cur), s2);
    s2 = m2 > 1.f ? 1.f : 0.f;  cnt += s2;
  };
  auto tree16 = [&](const float* t) -> float {
    const float a = (t[0]+t[1]) + (t[2]+t[3]);
    const float b = (t[4]+t[5]) + (t[6]+t[7]);
    const float c = (t[8]+t[9]) + (t[10]+t[11]);
    const float d = (t[12]+t[13]) + (t[14]+t[15]);
    return (a+b) + (c+d);
  };

  // one phase: read(t-1) issue | MFMA(t) | LIF(t+1) | write(t) | reduce(t-1) | barrier
  auto phase = [&](unsigned cur, unsigned prv, bool doRead, bool doLif) {
    float t[16];
    if (doRead)
#pragma unroll
      for (int s = 0; s < 16; ++s)
        t[s] = *(const float*)(lds + prv + rbase + (unsigned)(s*4096));
    f32x4_t acc[4] = {z4, z4, z4, z4};
#pragma unroll
    for (int ci = 0; ci < 2; ++ci)
#pragma unroll
      for (int nt = 0; nt < 4; ++nt)
        acc[nt] = __builtin_amdgcn_mfma_f32_16x16x32_bf16(afr[ci].v, bfr[ci][nt], acc[nt], 0,0,0);
    if (doLif) lif_step();
#pragma unroll
    for (int nt = 0; nt < 4; ++nt)
#pragma unroll
      for (int r = 0; r < 4; ++r)
        *(float*)(lds + cur + wbase + (unsigned)(r*512 + nt*128)) = acc[nt][r];
    if (doRead) l2_update(tree16(t) + b2l);
    __syncthreads();
  };

#pragma unroll 1
  for (int tt = 0; tt < NSTEPS; tt += 2) {
    phase(PB0, PB1, tt > 0, true);                 // t = tt
    phase(PB1, PB0, true,  tt + 1 < NSTEPS - 1);   // t = tt+1
  }
  // partials(t=99) sit in PB1; reduced below, folded into the NN phase.

  // ============ NN branch + final SNN reduce (reads PB1, writes PB0) ============
#pragma unroll
  for (int ci = 0; ci < 2; ++ci)
#pragma unroll
    for (int nt = 0; nt < 4; ++nt)
      bfr[ci][nt] = bfrag_f32(nn_w2 + (nt*16 + m)*1024 + (w*64 + ci*32) + q*8, 1.f);
  {
    // final SNN reduce (t = 99)
    float t[16];
#pragma unroll
    for (int s = 0; s < 16; ++s)
      t[s] = *(const float*)(lds + PB1 + rbase + (unsigned)(s*4096));
    l2_update(tree16(t) + b2l);

    // NN hidden + MFMA
    BF8U hfr[2];
    const int kb = w*64 + q*8;
#pragma unroll 1
    for (int ci = 0; ci < 2; ++ci) {
      const float* wp = nn_w1 + (kb + ci*32)*5;
      float wa[40];
#pragma unroll
      for (int u2 = 0; u2 < 10; ++u2) {
        const float4 t4 = *(const float4*)(wp + u2*4);
        wa[u2*4+0] = t4.x; wa[u2*4+1] = t4.y; wa[u2*4+2] = t4.z; wa[u2*4+3] = t4.w;
      }
      float hv[8];
#pragma unroll
      for (int j = 0; j < 8; ++j) {
        const float h = f0*wa[j*5] + f1*wa[j*5+1] + f2*wa[j*5+2] + f3*wa[j*5+3] + f4*wa[j*5+4]
                      + nn_b1[kb + ci*32 + j];
        hv[j] = fmaxf(h, 0.f);
      }
#pragma unroll
      for (int jj = 0; jj < 4; ++jj) hfr[ci].u[jj] = pack2bf(hv[2*jj], hv[2*jj+1]);
    }
    f32x4_t acc[4] = {z4, z4, z4, z4};
#pragma unroll
    for (int ci = 0; ci < 2; ++ci)
#pragma unroll
      for (int nt = 0; nt < 4; ++nt)
        acc[nt] = __builtin_amdgcn_mfma_f32_16x16x32_bf16(hfr[ci].v, bfr[ci][nt], acc[nt], 0,0,0);
#pragma unroll
    for (int nt = 0; nt < 4; ++nt)
#pragma unroll
      for (int r = 0; r < 4; ++r)
        *(float*)(lds + PB0 + wbase + (unsigned)(r*512 + nt*128)) = acc[nt][r];
  }
  __syncthreads();
  {
    float t[16];
#pragma unroll
    for (int s = 0; s < 16; ++s)
      t[s] = *(const float*)(lds + PB0 + rbase + (unsigned)(s*4096));
    const float nnv = tree16(t) + nn_b2[l];
    // comb inputs: snn count (scaled /128, fixed up in comb) and nn_out
    comb_store(lds, l,      w, cnt * 0.0078125f);
    comb_store(lds, 64 + l, w, nnv);
  }
  __syncthreads();

  // ======= CNN conv + relu + pairwise maxpool -> pooled bf16 frags [0,51200) =======
  {
    const int g  = tid >> 9;          // 0/1: position halves [0,25) / [25,50)
    const int ch = (tid >> 4) & 31;   // channel 0..31 (row = m)
    const float cw0 = conv_w[ch*3+0], cw1 = conv_w[ch*3+1], cw2 = conv_w[ch*3+2];
    const float cbb = conv_b[ch];
    const float* xw = xr + 5;
    const int p0 = g*25;
    float xm1 = (p0 == 0) ? 0.f : xw[2*p0 - 1];
    float x0v = xw[2*p0];
#pragma unroll 1
    for (int p = p0; p < p0 + 25; ++p) {
      const float xp1 = xw[2*p + 1];
      const float xp2 = (p < 49) ? xw[2*p + 2] : 0.f;
      const float av = cw0*xm1 + cw1*x0v + cw2*xp1 + cbb;
      const float bv = cw0*x0v + cw1*xp1 + cw2*xp2 + cbb;
      const float pv = fmaxf(fmaxf(av, 0.f), fmaxf(bv, 0.f));
      const int k = ch*50 + p;
      *(unsigned short*)(lds + (unsigned)((k>>5)*1024 + (((k>>3)&3)*16 + m)*16 + (k&7)*2)) = f2bfu(pv);
      xm1 = xp1; x0v = xp2;
    }
  }
  __syncthreads();

  // ================= CNN fc: wave w owns n-tile w, full K=1600 =================
  {
    const int c0 = w*16 + m;
    f32x4_t e0 = z4, o0 = z4;
    if (use_bf) {
#pragma unroll 2
      for (int kc = 0; kc < 50; kc += 2) {
        const bf16x8_t a0 = *(const bf16x8_t*)(lds + (unsigned)((kc*64 + l)*16));
        const bf16x8_t a1 = *(const bf16x8_t*)(lds + (unsigned)(((kc+1)*64 + l)*16));
        e0 = __builtin_amdgcn_mfma_f32_16x16x32_bf16(a0, *(const bf16x8_t*)(fcwb + c0*1600 + kc*32 + q*8), e0, 0,0,0);
        o0 = __builtin_amdgcn_mfma_f32_16x16x32_bf16(a1, *(const bf16x8_t*)(fcwb + c0*1600 + (kc+1)*32 + q*8), o0, 0,0,0);
      }
    } else {
#pragma unroll 2
      for (int kc = 0; kc < 50; kc += 2) {
        const bf16x8_t a0 = *(const bf16x8_t*)(lds + (unsigned)((kc*64 + l)*16));
        const bf16x8_t a1 = *(const bf16x8_t*)(lds + (unsigned)(((kc+1)*64 + l)*16));
        e0 = __builtin_amdgcn_mfma_f32_16x16x32_bf16(a0, bfrag_f32(fc_w + c0*1600 + kc*32 + q*8, 1.f), e0, 0,0,0);
        o0 = __builtin_amdgcn_mfma_f32_16x16x32_bf16(a1, bfrag_f32(fc_w + c0*1600 + (kc+1)*32 + q*8, 1.f), o0, 0,0,0);
      }
    }
    const float fb0 = fc_b[c0];
#pragma unroll
    for (int r = 0; r < 4; ++r)
      comb_store(lds, 128 + c0, q*4 + r, (e0[r] + o0[r]) + fb0);
  }
  __syncthreads();

  // ================= comb matmul: waves 0..3, wave w owns n-tile w, full K=384 =================
  if (w < 4) {
    const int cn = w*16 + m;
    f32x4_t oe = z4, oo = z4;
#pragma unroll
    for (int kc = 0; kc < 12; kc += 2) {
      const bf16x8_t a0 = *(const bf16x8_t*)(lds + COMBF + (unsigned)((kc*64 + l)*16));
      const bf16x8_t a1 = *(const bf16x8_t*)(lds + COMBF + (unsigned)(((kc+1)*64 + l)*16));
      const float s0 = (kc    < 2) ? 1.28f : 1.f;   // undo /128 on snn counts -> /100
      const float s1 = (kc+1 < 2) ? 1.28f : 1.f;
      oe = __builtin_amdgcn_mfma_f32_16x16x32_bf16(a0, bfrag_f32(comb_w + cn*384 + kc*32 + q*8, s0), oe, 0,0,0);
      oo = __builtin_amdgcn_mfma_f32_16x16x32_bf16(a1, bfrag_f32(comb_w + cn*384 + (kc+1)*32 + q*8, s1), oo, 0,0,0);
    }
    const float cb2 = comb_b[cn];
#pragma unroll
    for (int r = 0; r < 4; ++r)
      out[(row0 + q*4 + r)*64 + cn] = (oe[r] + oo[r]) + cb2;
  }
}

// fc_w fp32 -> bf16 (runs every call; d_ws is re-poisoned by the harness)
__global__ __launch_bounds__(256)
void fcw_to_bf16(const float* __restrict__ src, unsigned short* __restrict__ dst) {
  const int i = (blockIdx.x * 256 + threadIdx.x) * 4;
  const float4 v = *(const float4*)(src + i);
  ushort4 o;
  o.x = f2bfu(v.x); o.y = f2bfu(v.y); o.z = f2bfu(v.z); o.w = f2bfu(v.w);
  *(ushort4*)(dst + i) = o;
}

extern "C" void kernel_launch(void* const* d_in, const int* in_sizes, int n_in,
                              void* d_out, int out_size, void* d_ws, size_t ws_size,
                              hipStream_t stream) {
  const float* x       = (const float*)d_in[0];
  const float* snn_w1  = (const float*)d_in[1];
  const float* snn_b1  = (const float*)d_in[2];
  const float* snn_w2  = (const float*)d_in[3];
  const float* snn_b2  = (const float*)d_in[4];
  const float* nn_w1   = (const float*)d_in[5];
  const float* nn_b1   = (const float*)d_in[6];
  const float* nn_w2   = (const float*)d_in[7];
  const float* nn_b2   = (const float*)d_in[8];
  const float* conv_w  = (const float*)d_in[9];
  const float* conv_b  = (const float*)d_in[10];
  const float* fc_w    = (const float*)d_in[11];
  const float* fc_b    = (const float*)d_in[12];
  const float* comb_w  = (const float*)d_in[13];
  const float* comb_b  = (const float*)d_in[14];
  float* outp = (float*)d_out;

  const int rows = in_sizes[0] / 105;          // 16384
  const int grid = rows / 16;                  // 1024

  const size_t fcw_elems = (size_t)in_sizes[11];          // 256*1600 = 409600
  const int use_bf = (ws_size >= fcw_elems * 2) ? 1 : 0;
  unsigned short* fcwb = (unsigned short*)d_ws;
  if (use_bf) {
    fcw_to_bf16<<<dim3((unsigned)(fcw_elems / 1024)), dim3(256), 0, stream>>>(fc_w, fcwb);
  }

  hybrid_v8<<<dim3(grid), dim3(1024), 0, stream>>>(
      x, snn_w1, snn_b1, snn_w2, snn_b2,
      nn_w1, nn_b1, nn_w2, nn_b2,
      conv_w, conv_b, fc_w, fc_b, comb_w, comb_b,
      fcwb, use_bf, outp);
}

// Round 6
// 783.702 us; speedup vs baseline: 1.5163x; 1.5163x over previous
//
#include <hip/hip_runtime.h>

typedef __bf16 bf16x8_t __attribute__((ext_vector_type(8)));
typedef float f32x4_t __attribute__((ext_vector_type(4)));
typedef float f32x2_t __attribute__((ext_vector_type(2)));

#define NSTEPS 100
#define PB0 0u          // partial double-buffer: [0,64K) and [64K,128K)
#define PB1 65536u
#define COMBF 98304u    // comb-input bf16 fragments (post-loop, inside PB1 region)

static __device__ __forceinline__ unsigned short f2bfu(float v) {
  union { __bf16 h; unsigned short u; } c; c.h = (__bf16)v; return c.u;  // RTNE
}
static __device__ __forceinline__ unsigned int pack2bf(float a, float b) {
  return (unsigned)f2bfu(a) | ((unsigned)f2bfu(b) << 16);
}
union BF8U { unsigned int u[4]; bf16x8_t v; };

// VOP3P packed fp32, in-place. Per-half bitwise-identical to v_mul/v_add_f32.
static __device__ __forceinline__ void pk_mul_ip(f32x2_t &a, f32x2_t b) {
  asm("v_pk_mul_f32 %0, %0, %1" : "+v"(a) : "v"(b));
}
static __device__ __forceinline__ void pk_add_ip(f32x2_t &a, f32x2_t b) {
  asm("v_pk_add_f32 %0, %0, %1" : "+v"(a) : "v"(b));
}

static __device__ __forceinline__ bf16x8_t bfrag_f32(const float* __restrict__ p, float s) {
  BF8U r;
#pragma unroll
  for (int i = 0; i < 4; ++i) r.u[i] = pack2bf(p[2*i]*s, p[2*i+1]*s);
  return r.v;
}

static __device__ __forceinline__ void comb_store(unsigned char* ldsp, int k, int row, float v) {
  *(unsigned short*)(ldsp + COMBF +
      (unsigned)((k >> 5)*1024 + (((k >> 3) & 3)*16 + row)*16 + (k & 7)*2)) = f2bfu(v);
}

// 1024 threads = 16 waves = 4 waves/SIMD: hard 128-reg unified budget (64V+64A split).
// AGPR set: bfr 32 + acc 16 + afr 8 = 56. VGPR set: c2 16 + mem2 16 + misc ~25.
// Phase order MFMA->LIF->write->read keeps the read transients out of the MFMA window.
// Partial layout [slice][R][col ^ ((R>>2)<<4)] f32: writes AND reads 2 lanes/bank (free).
__global__ __launch_bounds__(1024, 4)
void hybrid_v9(const float* __restrict__ x,
               const float* __restrict__ snn_w1, const float* __restrict__ snn_b1,
               const float* __restrict__ snn_w2, const float* __restrict__ snn_b2,
               const float* __restrict__ nn_w1,  const float* __restrict__ nn_b1,
               const float* __restrict__ nn_w2,  const float* __restrict__ nn_b2,
               const float* __restrict__ conv_w, const float* __restrict__ conv_b,
               const float* __restrict__ fc_w,   const float* __restrict__ fc_b,
               const float* __restrict__ comb_w, const float* __restrict__ comb_b,
               const unsigned short* __restrict__ fcwb, int use_bf,
               float* __restrict__ out)
{
  __shared__ __align__(16) unsigned char lds[131072];
  const int tid  = threadIdx.x;
  const int w    = tid >> 6;        // wave 0..15: K-slice [64w, 64w+64)
  const int l    = tid & 63;
  const int q    = l >> 4;
  const int m    = l & 15;
  const int row0 = blockIdx.x * 16;

  const float* xr = x + (row0 + m)*105;
  const float f0 = xr[0], f1 = xr[1], f2 = xr[2], f3 = xr[3], f4 = xr[4];

  // layer-2 cell owned by this lane: (row = w, col = l)
  const float b2l = snn_b2[l];

  // resident snn_w2 B-fragments: 2 k-chunks x 4 n-tiles (32 regs, AGPR-eligible)
  bf16x8_t bfr[2][4];
#pragma unroll
  for (int ci = 0; ci < 2; ++ci)
#pragma unroll
    for (int nt = 0; nt < 4; ++nt)
      bfr[ci][nt] = bfrag_f32(snn_w2 + (nt*16 + m)*1024 + (w*64 + ci*32) + q*8, 1.f);

  // layer-1 LIF state: 16 cells/lane as 8 f32 pairs; staged in 4-neuron chunks
  f32x2_t c2[8], mem2[8];
  f32x2_t beta2; beta2.x = 0.95f; beta2.y = 0.95f;
  {
    const int kb = w*64 + q*8;
#pragma unroll
    for (int ci = 0; ci < 2; ++ci)
#pragma unroll
      for (int hf = 0; hf < 2; ++hf) {
        const float* wp = snn_w1 + (kb + ci*32 + hf*4)*5;
        float wa[20];
#pragma unroll
        for (int u = 0; u < 5; ++u) {
          const float4 t4 = *(const float4*)(wp + u*4);
          wa[u*4+0] = t4.x; wa[u*4+1] = t4.y; wa[u*4+2] = t4.z; wa[u*4+3] = t4.w;
        }
        float cc[4];
#pragma unroll
        for (int j = 0; j < 4; ++j)
          cc[j] = f0*wa[j*5] + f1*wa[j*5+1] + f2*wa[j*5+2] + f3*wa[j*5+3] + f4*wa[j*5+4]
                + snn_b1[kb + ci*32 + hf*4 + j];
#pragma unroll
        for (int jj = 0; jj < 2; ++jj) {
          f32x2_t t; t.x = cc[2*jj]; t.y = cc[2*jj+1];
          c2[ci*4 + hf*2 + jj] = t;
          f32x2_t z; z.x = 0.f; z.y = 0.f;
          mem2[ci*4 + hf*2 + jj] = z;
        }
      }
  }

  // spike A-fragments (8 regs, AGPR-eligible); reset derived from afr words (bit-exact)
  BF8U afr[2];
#pragma unroll
  for (int ci = 0; ci < 2; ++ci)
#pragma unroll
    for (int j = 0; j < 4; ++j) afr[ci].u[j] = 0u;

  auto lif_step = [&]() {
#pragma unroll
    for (int i = 0; i < 8; ++i) {
      const unsigned pw = afr[i>>2].u[i&3];
      f32x2_t sn;
      sn.x = __uint_as_float((pw << 16) | 0x80000000u);
      sn.y = __uint_as_float((pw & 0x3F800000u) | 0x80000000u);
      pk_mul_ip(mem2[i], beta2);      // mem = ((0.95*mem) + c) + (-sp)  [exact order]
      pk_add_ip(mem2[i], c2[i]);
      pk_add_ip(mem2[i], sn);
      const unsigned lo  = mem2[i].x > 1.f ? 0x3F80u     : 0u;
      const unsigned hi2 = mem2[i].y > 1.f ? 0x3F800000u : 0u;
      afr[i>>2].u[i&3] = lo | hi2;
    }
  };
  lif_step();                        // spikes(t=0)

  // layer-2 LIF (scalar: one cell per lane)
  float m2 = 0.f, s2 = 0.f, cnt = 0.f;

  // partial layout per buffer: addr = slice*4096 + R*256 + (col ^ ((R>>2)<<4))*4
  // write (wave w=slice, lane(q,m), C elem (R=q*4+r, col=nt*16+m)):
  //   vb[nt] = w*4096 + q*1024 + m*4 + ((nt^q)*64), + r*256
  // read (wave w=row R, lane col l): rb = w*256 + (l ^ ((w>>2)<<4))*4, + s*4096
  unsigned vb[4];
#pragma unroll
  for (int nt = 0; nt < 4; ++nt)
    vb[nt] = (unsigned)(w*4096 + q*1024 + m*4 + ((nt ^ q) * 64));
  const unsigned rb = (unsigned)(w*256 + ((l ^ ((w >> 2) << 4)) * 4));
  const f32x4_t z4 = {0.f, 0.f, 0.f, 0.f};

  auto l2_update = [&](float cur) {
    m2 = __fsub_rn(__fadd_rn(__fmul_rn(0.95f, m2), cur), s2);
    s2 = m2 > 1.f ? 1.f : 0.f;  cnt += s2;
  };

  // grouped reduce: same tree as before: ((s0+s1)+(s2+s3)) ... ((..)+(..))
  auto reduce_read = [&](unsigned prv) -> float {
    float g[4];
#pragma unroll
    for (int gi = 0; gi < 4; ++gi) {
      const float u0 = *(const float*)(lds + prv + rb + (unsigned)((gi*4+0)*4096));
      const float u1 = *(const float*)(lds + prv + rb + (unsigned)((gi*4+1)*4096));
      const float u2 = *(const float*)(lds + prv + rb + (unsigned)((gi*4+2)*4096));
      const float u3 = *(const float*)(lds + prv + rb + (unsigned)((gi*4+3)*4096));
      g[gi] = (u0+u1) + (u2+u3);
    }
    return (g[0]+g[1]) + (g[2]+g[3]);
  };

  // one phase: MFMA(t) | LIF(t+1) | write(t) | read+reduce(t-1) | barrier
  auto phase = [&](unsigned cur, unsigned prv, bool doRead, bool doLif) {
    f32x4_t acc[4] = {z4, z4, z4, z4};
#pragma unroll
    for (int ci = 0; ci < 2; ++ci)
#pragma unroll
      for (int nt = 0; nt < 4; ++nt)
        acc[nt] = __builtin_amdgcn_mfma_f32_16x16x32_bf16(afr[ci].v, bfr[ci][nt], acc[nt], 0,0,0);
    if (doLif) lif_step();
#pragma unroll
    for (int nt = 0; nt < 4; ++nt)
#pragma unroll
      for (int r = 0; r < 4; ++r)
        *(float*)(lds + cur + vb[nt] + (unsigned)(r*256)) = acc[nt][r];
    if (doRead) l2_update(reduce_read(prv) + b2l);
    __syncthreads();
  };

#pragma unroll 1
  for (int tt = 0; tt < NSTEPS; tt += 2) {
    phase(PB0, PB1, tt > 0, true);                 // t = tt
    phase(PB1, PB0, true,  tt + 1 < NSTEPS - 1);   // t = tt+1
  }
  // partials(t=99) sit in PB1; reduced below, folded into the NN phase.

  // ============ NN branch + final SNN reduce (reads PB1, writes PB0) ============
#pragma unroll
  for (int ci = 0; ci < 2; ++ci)
#pragma unroll
    for (int nt = 0; nt < 4; ++nt)
      bfr[ci][nt] = bfrag_f32(nn_w2 + (nt*16 + m)*1024 + (w*64 + ci*32) + q*8, 1.f);
  {
    // final SNN reduce (t = 99)
    l2_update(reduce_read(PB1) + b2l);

    // NN hidden + MFMA
    BF8U hfr[2];
    const int kb = w*64 + q*8;
#pragma unroll
    for (int ci = 0; ci < 2; ++ci) {
      const float* wp = nn_w1 + (kb + ci*32)*5;
      float wa[40];
#pragma unroll
      for (int u2 = 0; u2 < 10; ++u2) {
        const float4 t4 = *(const float4*)(wp + u2*4);
        wa[u2*4+0] = t4.x; wa[u2*4+1] = t4.y; wa[u2*4+2] = t4.z; wa[u2*4+3] = t4.w;
      }
      float hv[8];
#pragma unroll
      for (int j = 0; j < 8; ++j) {
        const float h = f0*wa[j*5] + f1*wa[j*5+1] + f2*wa[j*5+2] + f3*wa[j*5+3] + f4*wa[j*5+4]
                      + nn_b1[kb + ci*32 + j];
        hv[j] = fmaxf(h, 0.f);
      }
#pragma unroll
      for (int jj = 0; jj < 4; ++jj) hfr[ci].u[jj] = pack2bf(hv[2*jj], hv[2*jj+1]);
    }
    f32x4_t acc[4] = {z4, z4, z4, z4};
#pragma unroll
    for (int ci = 0; ci < 2; ++ci)
#pragma unroll
      for (int nt = 0; nt < 4; ++nt)
        acc[nt] = __builtin_amdgcn_mfma_f32_16x16x32_bf16(hfr[ci].v, bfr[ci][nt], acc[nt], 0,0,0);
#pragma unroll
    for (int nt = 0; nt < 4; ++nt)
#pragma unroll
      for (int r = 0; r < 4; ++r)
        *(float*)(lds + PB0 + vb[nt] + (unsigned)(r*256)) = acc[nt][r];
  }
  __syncthreads();
  {
    const float nnv = reduce_read(PB0) + nn_b2[l];
    // comb inputs: snn count (scaled /128, fixed up in comb) and nn_out
    comb_store(lds, l,      w, cnt * 0.0078125f);
    comb_store(lds, 64 + l, w, nnv);
  }
  __syncthreads();

  // ======= CNN conv + relu + pairwise maxpool -> pooled bf16 frags [0,51200) =======
  {
    const int g  = tid >> 9;          // 0/1: position halves [0,25) / [25,50)
    const int ch = (tid >> 4) & 31;   // channel 0..31 (row = m)
    const float cw0 = conv_w[ch*3+0], cw1 = conv_w[ch*3+1], cw2 = conv_w[ch*3+2];
    const float cbb = conv_b[ch];
    const float* xw = xr + 5;
    const int p0 = g*25;
    float xm1 = (p0 == 0) ? 0.f : xw[2*p0 - 1];
    float x0v = xw[2*p0];
#pragma unroll 1
    for (int p = p0; p < p0 + 25; ++p) {
      const float xp1 = xw[2*p + 1];
      const float xp2 = (p < 49) ? xw[2*p + 2] : 0.f;
      const float av = cw0*xm1 + cw1*x0v + cw2*xp1 + cbb;
      const float bv = cw0*x0v + cw1*xp1 + cw2*xp2 + cbb;
      const float pv = fmaxf(fmaxf(av, 0.f), fmaxf(bv, 0.f));
      const int k = ch*50 + p;
      *(unsigned short*)(lds + (unsigned)((k>>5)*1024 + (((k>>3)&3)*16 + m)*16 + (k&7)*2)) = f2bfu(pv);
      xm1 = xp1; x0v = xp2;
    }
  }
  __syncthreads();

  // ================= CNN fc: wave w owns n-tile w, full K=1600 =================
  {
    const int c0 = w*16 + m;
    f32x4_t e0 = z4, o0 = z4;
    if (use_bf) {
#pragma unroll 2
      for (int kc = 0; kc < 50; kc += 2) {
        const bf16x8_t a0 = *(const bf16x8_t*)(lds + (unsigned)((kc*64 + l)*16));
        const bf16x8_t a1 = *(const bf16x8_t*)(lds + (unsigned)(((kc+1)*64 + l)*16));
        e0 = __builtin_amdgcn_mfma_f32_16x16x32_bf16(a0, *(const bf16x8_t*)(fcwb + c0*1600 + kc*32 + q*8), e0, 0,0,0);
        o0 = __builtin_amdgcn_mfma_f32_16x16x32_bf16(a1, *(const bf16x8_t*)(fcwb + c0*1600 + (kc+1)*32 + q*8), o0, 0,0,0);
      }
    } else {
#pragma unroll 2
      for (int kc = 0; kc < 50; kc += 2) {
        const bf16x8_t a0 = *(const bf16x8_t*)(lds + (unsigned)((kc*64 + l)*16));
        const bf16x8_t a1 = *(const bf16x8_t*)(lds + (unsigned)(((kc+1)*64 + l)*16));
        e0 = __builtin_amdgcn_mfma_f32_16x16x32_bf16(a0, bfrag_f32(fc_w + c0*1600 + kc*32 + q*8, 1.f), e0, 0,0,0);
        o0 = __builtin_amdgcn_mfma_f32_16x16x32_bf16(a1, bfrag_f32(fc_w + c0*1600 + (kc+1)*32 + q*8, 1.f), o0, 0,0,0);
      }
    }
    const float fb0 = fc_b[c0];
#pragma unroll
    for (int r = 0; r < 4; ++r)
      comb_store(lds, 128 + c0, q*4 + r, (e0[r] + o0[r]) + fb0);
  }
  __syncthreads();

  // ================= comb matmul: waves 0..3, wave w owns n-tile w, full K=384 =================
  if (w < 4) {
    const int cn = w*16 + m;
    f32x4_t oe = z4, oo = z4;
#pragma unroll
    for (int kc = 0; kc < 12; kc += 2) {
      const bf16x8_t a0 = *(const bf16x8_t*)(lds + COMBF + (unsigned)((kc*64 + l)*16));
      const bf16x8_t a1 = *(const bf16x8_t*)(lds + COMBF + (unsigned)(((kc+1)*64 + l)*16));
      const float s0 = (kc    < 2) ? 1.28f : 1.f;   // undo /128 on snn counts -> /100
      const float s1 = (kc+1 < 2) ? 1.28f : 1.f;
      oe = __builtin_amdgcn_mfma_f32_16x16x32_bf16(a0, bfrag_f32(comb_w + cn*384 + kc*32 + q*8, s0), oe, 0,0,0);
      oo = __builtin_amdgcn_mfma_f32_16x16x32_bf16(a1, bfrag_f32(comb_w + cn*384 + (kc+1)*32 + q*8, s1), oo, 0,0,0);
    }
    const float cb2 = comb_b[cn];
#pragma unroll
    for (int r = 0; r < 4; ++r)
      out[(row0 + q*4 + r)*64 + cn] = (oe[r] + oo[r]) + cb2;
  }
}

// fc_w fp32 -> bf16 (runs every call; d_ws is re-poisoned by the harness)
__global__ __launch_bounds__(256)
void fcw_to_bf16(const float* __restrict__ src, unsigned short* __restrict__ dst) {
  const int i = (blockIdx.x * 256 + threadIdx.x) * 4;
  const float4 v = *(const float4*)(src + i);
  ushort4 o;
  o.x = f2bfu(v.x); o.y = f2bfu(v.y); o.z = f2bfu(v.z); o.w = f2bfu(v.w);
  *(ushort4*)(dst + i) = o;
}

extern "C" void kernel_launch(void* const* d_in, const int* in_sizes, int n_in,
                              void* d_out, int out_size, void* d_ws, size_t ws_size,
                              hipStream_t stream) {
  const float* x       = (const float*)d_in[0];
  const float* snn_w1  = (const float*)d_in[1];
  const float* snn_b1  = (const float*)d_in[2];
  const float* snn_w2  = (const float*)d_in[3];
  const float* snn_b2  = (const float*)d_in[4];
  const float* nn_w1   = (const float*)d_in[5];
  const float* nn_b1   = (const float*)d_in[6];
  const float* nn_w2   = (const float*)d_in[7];
  const float* nn_b2   = (const float*)d_in[8];
  const float* conv_w  = (const float*)d_in[9];
  const float* conv_b  = (const float*)d_in[10];
  const float* fc_w    = (const float*)d_in[11];
  const float* fc_b    = (const float*)d_in[12];
  const float* comb_w  = (const float*)d_in[13];
  const float* comb_b  = (const float*)d_in[14];
  float* outp = (float*)d_out;

  const int rows = in_sizes[0] / 105;          // 16384
  const int grid = rows / 16;                  // 1024

  const size_t fcw_elems = (size_t)in_sizes[11];          // 256*1600 = 409600
  const int use_bf = (ws_size >= fcw_elems * 2) ? 1 : 0;
  unsigned short* fcwb = (unsigned short*)d_ws;
  if (use_bf) {
    fcw_to_bf16<<<dim3((unsigned)(fcw_elems / 1024)), dim3(256), 0, stream>>>(fc_w, fcwb);
  }

  hybrid_v9<<<dim3(grid), dim3(1024), 0, stream>>>(
      x, snn_w1, snn_b1, snn_w2, snn_b2,
      nn_w1, nn_b1, nn_w2, nn_b2,
      conv_w, conv_b, fc_w, fc_b, comb_w, comb_b,
      fcwb, use_bf, outp);
}